// Round 11
// baseline (307.630 us; speedup 1.0000x reference)
//
#include <hip/hip_runtime.h>
#include <hip/hip_bf16.h>
#include <stdint.h>

#define ALPHA 1.0f

typedef __attribute__((ext_vector_type(8))) short bf16x8;
typedef __attribute__((ext_vector_type(4))) float f32x4;
typedef unsigned short ushort_t;

__device__ __forceinline__ unsigned short f32_to_bf16_rne(float f) {
    union { float f; unsigned int u; } v; v.f = f;
    unsigned int u = v.u;
    unsigned int r = u + 0x7FFFu + ((u >> 16) & 1u);
    return (unsigned short)(r >> 16);
}

__device__ __forceinline__ unsigned int cvt_pk_bf16(float lo, float hi) {
    unsigned int r;
    asm("v_cvt_pk_bf16_f32 %0, %1, %2" : "=v"(r) : "v"(lo), "v"(hi));
    return r;
}

__device__ __forceinline__ void async_copy16(const void* g, void* l) {
    __builtin_amdgcn_global_load_lds(
        (const __attribute__((address_space(1))) void*)g,
        (__attribute__((address_space(3))) void*)l, 16, 0, 0);
}

// ---------------------------------------------------------------------------
// Fused W_eff: weff[o][i] = W[o][i] + ALPHA * sum_r fac[o][r] * t1[r][i]
template <bool BF16OUT>
__global__ __launch_bounds__(256)
void weff_fused_kernel(const float* __restrict__ W,
                       const float* __restrict__ lora_down,
                       const float* __restrict__ lora_up,
                       const float* __restrict__ down_aux,
                       const float* __restrict__ up_aux,
                       void* __restrict__ weff) {
    int o = blockIdx.x;
    int i0 = threadIdx.x * 4;

    float fac[4] = {0.f, 0.f, 0.f, 0.f};
    for (int u = 0; u < 50; ++u) {
        float ua = up_aux[o * 50 + u] * ALPHA;
#pragma unroll
        for (int r = 0; r < 4; ++r) fac[r] += ua * lora_up[u * 4 + r];
    }

    float4 t1[4];
#pragma unroll
    for (int r = 0; r < 4; ++r) t1[r] = make_float4(0.f, 0.f, 0.f, 0.f);
    for (int d = 0; d < 100; ++d) {
        float4 da = *(const float4*)(down_aux + d * 1024 + i0);
#pragma unroll
        for (int r = 0; r < 4; ++r) {
            float ld = lora_down[r * 100 + d];
            t1[r].x += ld * da.x; t1[r].y += ld * da.y;
            t1[r].z += ld * da.z; t1[r].w += ld * da.w;
        }
    }

    float4 acc = *(const float4*)(W + (long)o * 1024 + i0);
#pragma unroll
    for (int r = 0; r < 4; ++r) {
        acc.x += fac[r] * t1[r].x; acc.y += fac[r] * t1[r].y;
        acc.z += fac[r] * t1[r].z; acc.w += fac[r] * t1[r].w;
    }

    if (BF16OUT) {
        ushort4 rr;
        rr.x = f32_to_bf16_rne(acc.x); rr.y = f32_to_bf16_rne(acc.y);
        rr.z = f32_to_bf16_rne(acc.z); rr.w = f32_to_bf16_rne(acc.w);
        *(ushort4*)((ushort_t*)weff + (long)o * 1024 + i0) = rr;
    } else {
        *(float4*)((float*)weff + (long)o * 1024 + i0) = acc;
    }
}

// ---------------------------------------------------------------------------
// Fused GEMM (m97-shaped): C = cvt_bf16(A_f32[M][K]) * Bt_bf16[N][K]^T + bias
// 128x128 tile, BK=32, 4 waves (2x2), per-wave 64x64 = acc[4][4] f32x4.
// ~24 KB LDS, ~125 regs -> ~3 blocks/CU: INTER-BLOCK TLP (m114/m97 mechanism)
// hides what static scheduling couldn't at 1 block/CU.
//
// Per iter: { loadA(j+1) f32->regs (4 gload); stageB(j+1)->Bb[o] (2 glds) }
//   issued at ITER TOP -> drained by sync1 ~900-1100 cyc later (covered);
//   frag reads (8 ds_read_b128) + 16 MFMA; sync1; writeA: 8 cvt_pk + 2
//   ds_write_b128 into As (single-buffer, readers done at sync1); sync2
//   (pure lgkm drain - VMEM queue is EMPTY here, avoiding R5's
//   issue-then-drain bug).
// Swizzle: 16B chunks, key(r) = (r&3)^((r>>2)&3) -> 2 lanes/bank (free) on
// both ds_write and frag reads; B glds uses pre-swizzled global source.
#define BM 128
#define BN 128
#define BK 32

__global__ __launch_bounds__(256, 3)
void gemm_fused_kernel(const float* __restrict__ A,
                       const ushort_t* __restrict__ Bt,
                       const float* __restrict__ bias,
                       float* __restrict__ C, int M, int N, int K) {
    __shared__ __align__(16) ushort_t As[BM * BK];      // 8 KB (single buf)
    __shared__ __align__(16) ushort_t Bb[2][BN * BK];   // 2 x 8 KB (dbuf)

    int nTilesN = N / BN;  // 8
    int nwg = gridDim.x;
    int bid = blockIdx.x;
    int swz = bid;
    if ((nwg & 7) == 0) {   // grid = 4096 -> bijective XCD swizzle
        int cpx = nwg >> 3;
        swz = (bid & 7) * cpx + (bid >> 3);
    }
    int tm = swz / nTilesN;   // 8 consecutive swz on one XCD share an A panel
    int tn = swz % nTilesN;
    const long rowA0 = (long)tm * BM;
    const long colB0 = (long)tn * BN;

    int tid = threadIdx.x;
    int lane = tid & 63;
    int wave = tid >> 6;       // 0..3
    int wr = wave >> 1;        // 0..1
    int wc = wave & 1;         // 0..1

    // ---- A staging map: thread covers rows r1 and r1+64, 32B f32 chunk cc --
    int r1 = tid >> 2;                       // 0..63
    int cc = tid & 3;                        // 8-f32 chunk within row
    int keyA = (r1 & 3) ^ ((r1 >> 2) & 3);   // same for r1+64
    int sA = cc ^ keyA;                      // stored bf16 16B-chunk

    // ---- B staging map (glds, pre-swizzled source) ----
    int brow[2], bcol[2];
#pragma unroll
    for (int q = 0; q < 2; ++q) {
        int pc = q * 256 + tid;
        brow[q] = pc >> 2;
        int kb = (brow[q] & 3) ^ ((brow[q] >> 2) & 3);
        bcol[q] = (pc & 3) ^ kb;
    }

    // ---- fragment map ----
    int fr = lane & 15;
    int h4 = lane >> 4;                      // 0..3 k-chunks
    int keyF = (fr & 3) ^ ((fr >> 2) & 3);
    int fchunk = (h4 ^ keyF) * 8;            // element offset in 32-elem row
    int aoff = (wr * 64 + fr) * BK;
    int boff = (wc * 64 + fr) * BK;

    f32x4 acc[4][4];
#pragma unroll
    for (int m = 0; m < 4; ++m)
#pragma unroll
        for (int n = 0; n < 4; ++n) acc[m][n] = (f32x4)(0.0f);

    const int nIter = K / BK;   // 32

    float4 vA[4];   // 16 regs: [0,1] row r1, [2,3] row r1+64

    auto loadA = [&](int kt) {
        const float* p = A + (rowA0 + r1) * (long)K + kt * BK + cc * 8;
        vA[0] = ((const float4*)p)[0];
        vA[1] = ((const float4*)p)[1];
        const float* p2 = p + 64 * (long)K;
        vA[2] = ((const float4*)p2)[0];
        vA[3] = ((const float4*)p2)[1];
    };
    auto writeA = [&]() {
        uint4 w;
        w.x = cvt_pk_bf16(vA[0].x, vA[0].y);
        w.y = cvt_pk_bf16(vA[0].z, vA[0].w);
        w.z = cvt_pk_bf16(vA[1].x, vA[1].y);
        w.w = cvt_pk_bf16(vA[1].z, vA[1].w);
        *(uint4*)&As[r1 * BK + sA * 8] = w;
        uint4 v;
        v.x = cvt_pk_bf16(vA[2].x, vA[2].y);
        v.y = cvt_pk_bf16(vA[2].z, vA[2].w);
        v.z = cvt_pk_bf16(vA[3].x, vA[3].y);
        v.w = cvt_pk_bf16(vA[3].z, vA[3].w);
        *(uint4*)&As[(r1 + 64) * BK + sA * 8] = v;
    };
    auto stageB = [&](int kt, int buf) {
#pragma unroll
        for (int q = 0; q < 2; ++q) {
            const ushort_t* src =
                Bt + (colB0 + brow[q]) * (long)K + kt * BK + bcol[q] * 8;
            ushort_t* dst = &Bb[buf][(q * 256 + wave * 64) * 8];
            async_copy16(src, dst);
        }
    };

    // ---------------- prologue ----------------
    loadA(0);
    stageB(0, 0);
    writeA();            // one-time HBM-latency wait (counted vmcnt)
    __syncthreads();     // drains stageB(0) + publishes As

    // ---------------- main loop: 2 syncs/iter, drains always covered -------
#pragma unroll 1
    for (int j = 0; j < nIter; ++j) {
        int c = j & 1, o = c ^ 1;
        bool more = (j + 1 < nIter);

        // issue next-tile loads at iter TOP (drained at sync1, ~1000cyc away)
        if (more) {
            loadA(j + 1);
            stageB(j + 1, o);
        }

        // fragment reads (tile j)
        bf16x8 a[4], b[4];
#pragma unroll
        for (int m = 0; m < 4; ++m)
            a[m] = *(const bf16x8*)&As[aoff + m * 16 * BK + fchunk];
#pragma unroll
        for (int n = 0; n < 4; ++n)
            b[n] = *(const bf16x8*)&Bb[c][boff + n * 16 * BK + fchunk];

        // 16 MFMA
#pragma unroll
        for (int m = 0; m < 4; ++m)
#pragma unroll
            for (int n = 0; n < 4; ++n)
                acc[m][n] = __builtin_amdgcn_mfma_f32_16x16x32_bf16(
                    a[m], b[n], acc[m][n], 0, 0, 0);

        __syncthreads();   // sync1: tile-j LDS reads done; drains vA + glds
                           // (both issued at top -> covered)

        if (more) writeA();  // cvt A(j+1) -> As (regs already arrived)

        __syncthreads();   // sync2: lgkm drain only (VMEM queue empty here)
    }

    // ---- epilogue: C = acc + bias ----
    int ccol = lane & 15;
    int crow = (lane >> 4) * 4;
#pragma unroll
    for (int m = 0; m < 4; ++m) {
        long grow = rowA0 + wr * 64 + m * 16 + crow;
#pragma unroll
        for (int n = 0; n < 4; ++n) {
            long gcol = colB0 + wc * 64 + n * 16 + ccol;
            float bb = bias[gcol];
#pragma unroll
            for (int r = 0; r < 4; ++r) {
                C[(grow + r) * N + gcol] = acc[m][n][r] + bb;
            }
        }
    }
}

// ---------------------------------------------------------------------------
// Fallback: plain f32 tiled GEMM (used only if ws too small for bf16 path)
__global__ __launch_bounds__(256)
void gemm_f32_fallback(const float* __restrict__ A, const float* __restrict__ Bt,
                       const float* __restrict__ bias, float* __restrict__ C,
                       int M, int N, int K) {
    __shared__ float As[64][17];
    __shared__ float Bs[64][17];
    int tilesN = N / 64;
    int tm = blockIdx.x / tilesN;
    int tn = blockIdx.x % tilesN;
    int tid = threadIdx.x;
    int tr = tid / 16, tc = tid % 16;
    float acc[4][4] = {};
    for (int k0 = 0; k0 < K; k0 += 16) {
        for (int t = tid; t < 64 * 16; t += 256) {
            int r = t / 16, c = t % 16;
            As[r][c] = A[((long)tm * 64 + r) * K + k0 + c];
            Bs[r][c] = Bt[((long)tn * 64 + r) * K + k0 + c];
        }
        __syncthreads();
#pragma unroll
        for (int kk = 0; kk < 16; ++kk) {
            float av[4], bv[4];
#pragma unroll
            for (int i = 0; i < 4; ++i) av[i] = As[tr * 4 + i][kk];
#pragma unroll
            for (int j = 0; j < 4; ++j) bv[j] = Bs[tc * 4 + j][kk];
#pragma unroll
            for (int i = 0; i < 4; ++i)
#pragma unroll
                for (int j = 0; j < 4; ++j) acc[i][j] += av[i] * bv[j];
        }
        __syncthreads();
    }
#pragma unroll
    for (int i = 0; i < 4; ++i) {
        long row = (long)tm * 64 + tr * 4 + i;
#pragma unroll
        for (int j = 0; j < 4; ++j) {
            long col = (long)tn * 64 + tc * 4 + j;
            C[row * N + col] = acc[i][j] + bias[col];
        }
    }
}

// ---------------------------------------------------------------------------
extern "C" void kernel_launch(void* const* d_in, const int* in_sizes, int n_in,
                              void* d_out, int out_size, void* d_ws, size_t ws_size,
                              hipStream_t stream) {
    const float* hs        = (const float*)d_in[0];
    const float* W         = (const float*)d_in[1];
    const float* b         = (const float*)d_in[2];
    const float* lora_down = (const float*)d_in[3];
    const float* lora_up   = (const float*)d_in[4];
    const float* down_aux  = (const float*)d_in[5];
    const float* up_aux    = (const float*)d_in[6];
    float* out = (float*)d_out;

    const int K = 1024;   // IN
    const int N = 1024;   // OUT
    const int M = in_sizes[0] / K;  // B*S = 65536

    char* ws = (char*)d_ws;
    const size_t NEED_FAST = 2 * 1024 * 1024;   // weff bf16 only

    if (ws_size >= NEED_FAST && (M % BM) == 0) {
        ushort_t* weff = (ushort_t*)ws;
        weff_fused_kernel<true><<<N, 256, 0, stream>>>(W, lora_down, lora_up,
                                                       down_aux, up_aux, weff);
        int grid = (M / BM) * (N / BN);   // 4096
        gemm_fused_kernel<<<grid, 256, 0, stream>>>(hs, weff, b, out, M, N, K);
    } else {
        float* weff = (float*)ws;  // 4MB
        weff_fused_kernel<false><<<N, 256, 0, stream>>>(W, lora_down, lora_up,
                                                        down_aux, up_aux, weff);
        int grid = (M / 64) * (N / 64);
        gemm_f32_fallback<<<grid, 256, 0, stream>>>(hs, weff, b, out, M, N, K);
    }
}